// Round 7
// baseline (101.990 us; speedup 1.0000x reference)
//
#include <hip/hip_runtime.h>
#include <math.h>

#define NB 32
#define NH 128
#define NW 128
#define NC 3
#define NF 2
#define NQ 9
#define NL 2
#define I0 126
#define I1 126
#define NPIX (NB * I0 * I1)          // 508,032
#define PPB 128                      // pixels per block (contiguous)
#define TPB 576                      // 18 q18-slots * 32 px lanes = 9 waves
#define NBLK (NPIX / PPB)            // 3969, exact
#define INV2PI 0.15915494309189535f

struct f3 { float x, y, z; };
typedef float f4 __attribute__((ext_vector_type(4)));   // native vec for nontemporal

__global__ __launch_bounds__(TPB) void qconv_fused(
        const float* __restrict__ x,
        const float* __restrict__ w_enc,
        const float* __restrict__ a_rz,
        const float* __restrict__ b_ry,
        float* __restrict__ out) {
    // coefficient table: row t = f*27 + c*9 + q :
    // [w*inv2pi, Rs.x,Rs.y,Rs.z, Rc.x,Rc.y,Rc.z, pad]
    __shared__ float stab[54 * 8];
    // output staging: exact image of out[pixbase*54 .. +6912)
    __shared__ float sout[PPB * 54];

    int tid = threadIdx.x;
    if (tid < 54) {
        int t = tid;
        int f = t / 27;
        int c = (t / 9) % 3;
        int q = t % 9;
        float ux = 1.f, uy = 0.f, uz = 0.f;   // image of e0
        float wx = 0.f, wy = 0.f, wz = 1.f;   // image of e2
#pragma unroll
        for (int l = 0; l < NL; ++l) {
            int ia = ((f * NC + c) * NL + l) * NQ + q;
            float sa, ca, sb, cb;
            __sincosf(a_rz[ia], &sa, &ca);
            __sincosf(b_ry[ia], &sb, &cb);
            float nx, ny, nz;
            nx = ux * ca - uy * sa; ny = ux * sa + uy * ca; ux = nx; uy = ny;
            nx = ux * cb + uz * sb; nz = -ux * sb + uz * cb; ux = nx; uz = nz;
            nx = wx * ca - wy * sa; ny = wx * sa + wy * ca; wx = nx; wy = ny;
            nx = wx * cb + wz * sb; nz = -wx * sb + wz * cb; wx = nx; wz = nz;
        }
        float* o = stab + t * 8;
        o[0] = w_enc[t] * INV2PI;
        o[1] = ux; o[2] = uy; o[3] = uz;
        o[4] = wx; o[5] = wy; o[6] = wz;
        o[7] = 0.f;
    }
    __syncthreads();

    // thread = (q18, pxl): fixed (f,q) -> coefficients live in registers
    int q18 = tid >> 5;                 // 0..17
    int pxl = tid & 31;                 // 0..31
    int f = (q18 >= 9) ? 1 : 0;
    int q = q18 - f * 9;
    int di = q / 3, dj = q - di * 3;

    float cw[3], sx[3], sy[3], sz[3], cx[3], cy[3], cz[3];
#pragma unroll
    for (int c = 0; c < 3; ++c) {
        const float* r = stab + (size_t)(f * 27 + c * 9 + q) * 8;
        float4 v0 = *reinterpret_cast<const float4*>(r);
        float4 v1 = *reinterpret_cast<const float4*>(r + 4);
        cw[c] = v0.x; sx[c] = v0.y; sy[c] = v0.z; sz[c] = v0.w;
        cx[c] = v1.x; cy[c] = v1.y; cz[c] = v1.z;
    }

    int pixbase = blockIdx.x * PPB;

#pragma unroll
    for (int k = 0; k < 4; ++k) {
        int px  = pixbase + pxl + 32 * k;
        int b   = px / (I0 * I1);              // magic-div (constants)
        int rem = px - b * (I0 * I1);
        int i   = rem / I1;
        int j   = rem - i * I1;

        const float* pp = x + ((size_t)((b * NH + i + di) * NW) + (j + dj)) * NC;
        f3 P = *reinterpret_cast<const f3*>(pp);

        float a0 = 0.f, a1 = 0.f, a2 = 0.f;
#pragma unroll
        for (int c = 0; c < 3; ++c) {
            float pc = (c == 0) ? P.x : (c == 1) ? P.y : P.z;
            float xr = pc * cw[c];
            float s  = __builtin_amdgcn_sinf(xr);
            float co = __builtin_amdgcn_cosf(xr);
            a0 = fmaf(sx[c], s, fmaf(cx[c], co, a0));
            a1 = fmaf(sy[c], s, fmaf(cy[c], co, a1));
            a2 = fmaf(sz[c], s, fmaf(cz[c], co, a2));
        }

        float* so = sout + (size_t)(pxl + 32 * k) * 54 + q18 * 3;
        so[0] = fmaxf(a0, 0.f);
        so[1] = fmaxf(a1, 0.f);
        so[2] = fmaxf(a2, 0.f);
    }
    __syncthreads();

    // dense writeback: 6912 floats = 1728 float4 = 3 per thread, 16B/lane
    const f4* s4 = reinterpret_cast<const f4*>(sout);
    f4* o4 = reinterpret_cast<f4*>(out + (size_t)pixbase * 54);
#pragma unroll
    for (int m = 0; m < 3; ++m) {
        __builtin_nontemporal_store(s4[tid * 3 + m], o4 + tid * 3 + m);
    }
}

extern "C" void kernel_launch(void* const* d_in, const int* in_sizes, int n_in,
                              void* d_out, int out_size, void* d_ws, size_t ws_size,
                              hipStream_t stream) {
    const float* x     = (const float*)d_in[0];
    const float* w_enc = (const float*)d_in[1];
    const float* a_rz  = (const float*)d_in[2];
    const float* b_ry  = (const float*)d_in[3];
    float* out = (float*)d_out;

    qconv_fused<<<NBLK, TPB, 0, stream>>>(x, w_enc, a_rz, b_ry, out);
}

// Round 8
// 30.319 us; speedup vs baseline: 3.3639x; 3.3639x over previous
//
#include <hip/hip_runtime.h>
#include <math.h>

#define NB 32
#define NH 128
#define NW 128
#define NC 3
#define NF 2
#define NQ 9
#define NL 2
#define I0 126
#define I1 126
#define NPIX (NB * I0 * I1)          // 508,032
#define PPB 128                      // pixels per block (contiguous)
#define TPB 576                      // 18 q18-slots * 32 px lanes = 9 waves
#define NBLK (NPIX / PPB)            // 3969, exact
#define INV2PI 0.15915494309189535f

struct f3 { float x, y, z; };
typedef float f4 __attribute__((ext_vector_type(4)));

__global__ __launch_bounds__(TPB) void qconv_fused(
        const float* __restrict__ x,
        const float* __restrict__ w_enc,
        const float* __restrict__ a_rz,
        const float* __restrict__ b_ry,
        float* __restrict__ out) {
    // coefficient table: row t = f*27 + c*9 + q :
    // [w*inv2pi, Rs.x,Rs.y,Rs.z, Rc.x,Rc.y,Rc.z, pad]
    __shared__ float stab[54 * 8];
    // output staging: exact image of out[pixbase*54 .. +6912)
    __shared__ float sout[PPB * 54];

    int tid = threadIdx.x;
    if (tid < 54) {
        int t = tid;
        int f = t / 27;
        int c = (t / 9) % 3;
        int q = t % 9;
        float ux = 1.f, uy = 0.f, uz = 0.f;   // image of e0
        float wx = 0.f, wy = 0.f, wz = 1.f;   // image of e2
#pragma unroll
        for (int l = 0; l < NL; ++l) {
            int ia = ((f * NC + c) * NL + l) * NQ + q;
            float sa, ca, sb, cb;
            __sincosf(a_rz[ia], &sa, &ca);
            __sincosf(b_ry[ia], &sb, &cb);
            float nx, ny, nz;
            nx = ux * ca - uy * sa; ny = ux * sa + uy * ca; ux = nx; uy = ny;
            nx = ux * cb + uz * sb; nz = -ux * sb + uz * cb; ux = nx; uz = nz;
            nx = wx * ca - wy * sa; ny = wx * sa + wy * ca; wx = nx; wy = ny;
            nx = wx * cb + wz * sb; nz = -wx * sb + wz * cb; wx = nx; wz = nz;
        }
        float* o = stab + t * 8;
        o[0] = w_enc[t] * INV2PI;
        o[1] = ux; o[2] = uy; o[3] = uz;
        o[4] = wx; o[5] = wy; o[6] = wz;
        o[7] = 0.f;
    }
    __syncthreads();

    // thread = (q18, pxl): fixed (f,q) -> coefficients live in registers
    int q18 = tid >> 5;                 // 0..17
    int pxl = tid & 31;                 // 0..31
    int f = (q18 >= 9) ? 1 : 0;
    int q = q18 - f * 9;
    int di = q / 3, dj = q - di * 3;

    float cw[3], sx[3], sy[3], sz[3], cx[3], cy[3], cz[3];
#pragma unroll
    for (int c = 0; c < 3; ++c) {
        const float* r = stab + (size_t)(f * 27 + c * 9 + q) * 8;
        float4 v0 = *reinterpret_cast<const float4*>(r);
        float4 v1 = *reinterpret_cast<const float4*>(r + 4);
        cw[c] = v0.x; sx[c] = v0.y; sy[c] = v0.z; sz[c] = v0.w;
        cx[c] = v1.x; cy[c] = v1.y; cz[c] = v1.z;
    }

    int pixbase = blockIdx.x * PPB;

#pragma unroll
    for (int k = 0; k < 4; ++k) {
        int px  = pixbase + pxl + 32 * k;
        int b   = px / (I0 * I1);              // magic-div (constants)
        int rem = px - b * (I0 * I1);
        int i   = rem / I1;
        int j   = rem - i * I1;

        const float* pp = x + ((size_t)((b * NH + i + di) * NW) + (j + dj)) * NC;
        f3 P = *reinterpret_cast<const f3*>(pp);

        float a0 = 0.f, a1 = 0.f, a2 = 0.f;
#pragma unroll
        for (int c = 0; c < 3; ++c) {
            float pc = (c == 0) ? P.x : (c == 1) ? P.y : P.z;
            float xr = pc * cw[c];
            float s  = __builtin_amdgcn_sinf(xr);
            float co = __builtin_amdgcn_cosf(xr);
            a0 = fmaf(sx[c], s, fmaf(cx[c], co, a0));
            a1 = fmaf(sy[c], s, fmaf(cy[c], co, a1));
            a2 = fmaf(sz[c], s, fmaf(cz[c], co, a2));
        }

        float* so = sout + (size_t)(pxl + 32 * k) * 54 + q18 * 3;
        so[0] = fmaxf(a0, 0.f);
        so[1] = fmaxf(a1, 0.f);
        so[2] = fmaxf(a2, 0.f);
    }
    __syncthreads();

    // dense writeback: 6912 floats = 1728 float4 = 3 per thread.
    // index [m*TPB + tid]: within one instruction lanes are 16B apart
    // -> each wave store covers a contiguous 1KB block, full 64B lines.
    const f4* s4 = reinterpret_cast<const f4*>(sout);
    f4* o4 = reinterpret_cast<f4*>(out + (size_t)pixbase * 54);
#pragma unroll
    for (int m = 0; m < 3; ++m) {
        o4[m * TPB + tid] = s4[m * TPB + tid];
    }
}

extern "C" void kernel_launch(void* const* d_in, const int* in_sizes, int n_in,
                              void* d_out, int out_size, void* d_ws, size_t ws_size,
                              hipStream_t stream) {
    const float* x     = (const float*)d_in[0];
    const float* w_enc = (const float*)d_in[1];
    const float* a_rz  = (const float*)d_in[2];
    const float* b_ry  = (const float*)d_in[3];
    float* out = (float*)d_out;

    qconv_fused<<<NBLK, TPB, 0, stream>>>(x, w_enc, a_rz, b_ry, out);
}

// Round 9
// 26.986 us; speedup vs baseline: 3.7793x; 1.1235x over previous
//
#include <hip/hip_runtime.h>
#include <math.h>

#define NB 32
#define NH 128
#define NW 128
#define NC 3
#define NF 2
#define NQ 9
#define NL 2
#define I0 126
#define I1 126
#define NPIX (NB * I0 * I1)          // 508,032
#define NWORK (NPIX * 18)            // 9,144,576
#define GTHREADS 1016064             // 3969 blocks * 256; NWORK / 9
#define DPIX 56448                   // GTHREADS / 18 pixels advanced per iter
#define INV2PI 0.15915494309189535f

struct f3 { float x, y, z; };        // 4B-aligned triple -> dwordx3

__global__ __launch_bounds__(256) void qconv_fused(
        const float* __restrict__ x,
        const float* __restrict__ w_enc,
        const float* __restrict__ a_rz,
        const float* __restrict__ b_ry,
        float* __restrict__ out) {
    // ---- per-block coefficient table build (threads 0..53) ----
    // row t = f*27 + c*9 + q : [w*inv2pi, Rs.x,Rs.y,Rs.z, Rc.x,Rc.y,Rc.z, pad]
    __shared__ float stab[54 * 8];
    int tid = threadIdx.x;
    if (tid < 54) {
        int t = tid;
        int f = t / 27;
        int c = (t / 9) % 3;
        int q = t % 9;
        float ux = 1.f, uy = 0.f, uz = 0.f;   // image of e0
        float wx = 0.f, wy = 0.f, wz = 1.f;   // image of e2
#pragma unroll
        for (int l = 0; l < NL; ++l) {
            int ia = ((f * NC + c) * NL + l) * NQ + q;
            float sa, ca, sb, cb;
            __sincosf(a_rz[ia], &sa, &ca);
            __sincosf(b_ry[ia], &sb, &cb);
            float nx, ny, nz;
            nx = ux * ca - uy * sa; ny = ux * sa + uy * ca; ux = nx; uy = ny;
            nx = ux * cb + uz * sb; nz = -ux * sb + uz * cb; ux = nx; uz = nz;
            nx = wx * ca - wy * sa; ny = wx * sa + wy * ca; wx = nx; wy = ny;
            nx = wx * cb + wz * sb; nz = -wx * sb + wz * cb; wx = nx; wz = nz;
        }
        float* o = stab + t * 8;
        o[0] = w_enc[t] * INV2PI;
        o[1] = ux; o[2] = uy; o[3] = uz;
        o[4] = wx; o[5] = wy; o[6] = wz;
        o[7] = 0.f;
    }
    __syncthreads();

    // ---- per-thread setup ----
    int T0 = blockIdx.x * 256 + tid;             // < GTHREADS
    int pixb = T0 / 18;
    int q18 = T0 - pixb * 18;
    int f = (q18 >= 9) ? 1 : 0;
    int q = q18 - f * 9;
    int di = q / 3, dj = q - di * 3;

    float cw[3], sx[3], sy[3], sz[3], cx[3], cy[3], cz[3];
#pragma unroll
    for (int c = 0; c < 3; ++c) {
        const float* r = stab + (size_t)(f * 27 + c * 9 + q) * 8;
        float4 v0 = *reinterpret_cast<const float4*>(r);
        float4 v1 = *reinterpret_cast<const float4*>(r + 4);
        cw[c] = v0.x; sx[c] = v0.y; sy[c] = v0.z; sz[c] = v0.w;
        cx[c] = v1.x; cy[c] = v1.y; cz[c] = v1.z;
    }

    int b   = pixb / (I0 * I1);
    int rem = pixb - b * (I0 * I1);
    int i   = rem / I1;
    int j   = rem - i * I1;

    int icur = i;
    const float* pin = x + ((size_t)((b * NH + i + di) * NW) + (j + dj)) * NC;
    float* pout = out + (size_t)pixb * 54 + q18 * 3;

    const long STEP_IN  = 454L * NW * NC;        // +DPIX pixels: 454 rows
    const long WRAP_IN  = 2L * NW * NC;          // i-wrap: +2 rows extra
    const long STEP_OUT = (long)DPIX * 54;

#define ADVANCE()  do { icur += 70; pin += STEP_IN; \
                        if (icur >= I0) { icur -= I0; pin += WRAP_IN; } } while (0)

#define COMPUTE_STORE(P, OP) do {                                   \
        float a0 = 0.f, a1 = 0.f, a2 = 0.f;                         \
        _Pragma("unroll")                                           \
        for (int c = 0; c < 3; ++c) {                               \
            float pc = (c == 0) ? (P).x : (c == 1) ? (P).y : (P).z; \
            float xr = pc * cw[c];                                  \
            float s  = __builtin_amdgcn_sinf(xr);                   \
            float co = __builtin_amdgcn_cosf(xr);                   \
            a0 = fmaf(sx[c], s, fmaf(cx[c], co, a0));               \
            a1 = fmaf(sy[c], s, fmaf(cy[c], co, a1));               \
            a2 = fmaf(sz[c], s, fmaf(cz[c], co, a2));               \
        }                                                           \
        f3 r_;                                                      \
        r_.x = fmaxf(a0, 0.f);                                      \
        r_.y = fmaxf(a1, 0.f);                                      \
        r_.z = fmaxf(a2, 0.f);                                      \
        *reinterpret_cast<f3*>(OP) = r_;                            \
    } while (0)

#pragma unroll
    for (int g = 0; g < 3; ++g) {
        const float* pA = pin; ADVANCE();
        const float* pB = pin; ADVANCE();
        const float* pC = pin; ADVANCE();
        f3 PA = *reinterpret_cast<const f3*>(pA);
        f3 PB = *reinterpret_cast<const f3*>(pB);
        f3 PC = *reinterpret_cast<const f3*>(pC);

        COMPUTE_STORE(PA, pout);
        COMPUTE_STORE(PB, pout + STEP_OUT);
        COMPUTE_STORE(PC, pout + 2 * STEP_OUT);
        pout += 3 * STEP_OUT;
    }
#undef ADVANCE
#undef COMPUTE_STORE
}

extern "C" void kernel_launch(void* const* d_in, const int* in_sizes, int n_in,
                              void* d_out, int out_size, void* d_ws, size_t ws_size,
                              hipStream_t stream) {
    const float* x     = (const float*)d_in[0];
    const float* w_enc = (const float*)d_in[1];
    const float* a_rz  = (const float*)d_in[2];
    const float* b_ry  = (const float*)d_in[3];
    float* out = (float*)d_out;

    int block = 256;
    int grid = GTHREADS / block;   // 3969
    qconv_fused<<<grid, block, 0, stream>>>(x, w_enc, a_rz, b_ry, out);
}